// Round 2
// 3196.282 us; speedup vs baseline: 1.1399x; 1.1399x over previous
//
#include <hip/hip_runtime.h>
#include <hip/hip_bf16.h>

#define VOCAB 32000
#define HID 512
#define BATCH 256
#define SEQ 128
#define NL 5
#define BH (BATCH*HID)      // 131072
#define G4H (4*HID)         // 2048
#define NBLK 160            // 5 layers x 32 column-slices, 1 block/CU

typedef __attribute__((ext_vector_type(8))) short short8;
typedef __attribute__((ext_vector_type(4))) float float4v;
typedef __attribute__((ext_vector_type(4))) unsigned int uint4v;

__device__ __forceinline__ float sigmoid_f(float x) {
    return 1.f / (1.f + __expf(-x));
}
__device__ __forceinline__ float tanh_f(float x) {
    float ax = fabsf(x);
    float e = __expf(2.f * ax);
    float t = 1.f - 2.f / (e + 1.f);
    return copysignf(t, x);
}
__device__ __forceinline__ short bf16bits(float f) {
    union { __hip_bfloat16 b; short s; } u;
    u.b = __float2bfloat16(f);
    return u.s;
}
__device__ __forceinline__ short8 load8f(const float* p) {   // fp32 -> bf16 frag
    float4v lo = *(const float4v*)p;
    float4v hi = *(const float4v*)(p + 4);
    short8 r;
    r[0] = bf16bits(lo[0]); r[1] = bf16bits(lo[1]);
    r[2] = bf16bits(lo[2]); r[3] = bf16bits(lo[3]);
    r[4] = bf16bits(hi[0]); r[5] = bf16bits(hi[1]);
    r[6] = bf16bits(hi[2]); r[7] = bf16bits(hi[3]);
    return r;
}
__device__ __forceinline__ short8 load8b(const __hip_bfloat16* p) {
    return *(const short8*)p;
}

// ---------------------------------------------------------------------------
// LLC-direct (bypass L1+L2) wide load/store via raw buffer ops.
// aux = SC0|SC1 = 17 on gfx950: served at the coherence point (Infinity
// Cache), never from a stale per-XCD L2 or per-CU L1. One 16B instruction
// per fragment -> full-line coalescing at the TA (vs 2x8B atomic-path ops).
// This ROCm's buffer builtins take an opaque __amdgpu_buffer_rsrc_t, built
// via __builtin_amdgcn_make_buffer_rsrc (same SRD words as hand-packed).
// ---------------------------------------------------------------------------
#if __has_builtin(__builtin_amdgcn_make_buffer_rsrc) && \
    __has_builtin(__builtin_amdgcn_raw_buffer_load_b128) && \
    __has_builtin(__builtin_amdgcn_raw_buffer_store_b128)
#define USE_BUFFER_OPS 1
typedef __amdgpu_buffer_rsrc_t srd_t;
__device__ __forceinline__ srd_t make_srd(const void* p) {
    // stride=0, num_records=0xFFFFFFFF (bounds check off), flags word3
    return __builtin_amdgcn_make_buffer_rsrc(const_cast<void*>(p), (short)0,
                                             0xFFFFFFFFu, 0x00020000);
}
__device__ __forceinline__ short8 bload16(srd_t srd, int voff, int soff) {
    union { uint4v u; short8 s; } c;
    c.u = __builtin_amdgcn_raw_buffer_load_b128(srd, voff, soff, 17);
    return c.s;
}
__device__ __forceinline__ void bstore16(short8 v, srd_t srd, int voff) {
    union { uint4v u; short8 s; } c; c.s = v;
    __builtin_amdgcn_raw_buffer_store_b128(c.u, srd, voff, 0, 17);
}
#else
#define USE_BUFFER_OPS 0
typedef const char* srd_t;
__device__ __forceinline__ srd_t make_srd(const void* p) {
    return (const char*)p;
}
__device__ __forceinline__ short8 bload16(srd_t srd, int voff, int soff) {
    const char* base = srd + voff + soff;
    union { unsigned long long q[2]; short8 s; } u;
    u.q[0] = __hip_atomic_load((const unsigned long long*)base,
                               __ATOMIC_RELAXED, __HIP_MEMORY_SCOPE_AGENT);
    u.q[1] = __hip_atomic_load((const unsigned long long*)(base + 8),
                               __ATOMIC_RELAXED, __HIP_MEMORY_SCOPE_AGENT);
    return u.s;
}
__device__ __forceinline__ void bstore16(short8 v, srd_t srd, int voff) {
    char* base = const_cast<char*>(srd) + voff;
    union { unsigned long long q[2]; short8 s; } u; u.s = v;
    __hip_atomic_store((unsigned long long*)base, u.q[0],
                       __ATOMIC_RELAXED, __HIP_MEMORY_SCOPE_AGENT);
    __hip_atomic_store((unsigned long long*)(base + 8), u.q[1],
                       __ATOMIC_RELAXED, __HIP_MEMORY_SCOPE_AGENT);
}
#endif

// h layout: slice-contiguous [p][l][j(32)][m(256)][c(16)] bf16
__device__ __forceinline__ size_t hidx(int p, int l, int j, int m, int c) {
    return ((((size_t)p * NL + l) * 32 + j) * 256 + m) * 16 + c;
}

// ---------------------------------------------------------------------------
// init: h0 fp32 -> parity-1 bf16 h buffer (slice layout); zero done counters
// ---------------------------------------------------------------------------
__global__ void init_state_k(const float* __restrict__ h0,
                             __hip_bfloat16* __restrict__ hbuf,
                             int* __restrict__ done) {
    int i = blockIdx.x * 256 + threadIdx.x;   // grid covers NL*BH exactly
    int l = i / BH, r = i % BH;
    int m = r >> 9, col = r & 511;
    hbuf[hidx(1, l, col >> 4, m, col & 15)] = __float2bfloat16(h0[i]);
    if (blockIdx.x == 0 && threadIdx.x < NL) done[threadIdx.x * 64] = 0;
}

// ---------------------------------------------------------------------------
// persistent wavefront LSTM. block = (layer l, 16-col slice j); 16 waves,
// wave w owns rows [16w,16w+16). Weights bf16 in LDS (128 KB, frag order).
// c in registers. h exchanged via 16B LLC-direct buffer ops (sc0|sc1,
// coalescable, depth-4 prefetch). Flags: monotonic counters.
// ---------------------------------------------------------------------------
__global__ __launch_bounds__(1024) void lstm_persist_k(
    const int* __restrict__ x,
    const float* __restrict__ emb,
    const float* __restrict__ W_ih,
    const float* __restrict__ W_hh,
    const float* __restrict__ b_ih,
    const float* __restrict__ b_hh,
    const float* __restrict__ c0,
    __hip_bfloat16* __restrict__ hbuf,
    int* __restrict__ done)
{
    __shared__ short lw[65536];               // 128 KB weight slice
    __shared__ short8 xch[16][32];            // 8 KB per-wave store transpose

    const int tid = threadIdx.x;
    const int xcd = blockIdx.x & 7;
    const int ixc = blockIdx.x >> 3;
    const int slot = xcd * 20 + ixc;          // XCD-contiguous slots
    const int l = slot >> 5;                  // layer 0..4
    const int j = slot & 31;                  // col slice 0..31
    const int jbase = j << 4;

    const int wave = tid >> 6, lane = tid & 63;
    const int quad = lane >> 4, l16 = lane & 15;
    const int m16 = wave << 4;

    const float* Wg[2] = { W_ih + (size_t)l * G4H * HID,
                           W_hh + (size_t)l * G4H * HID };

    // ---- stage weight slice into LDS in fragment order ----
    for (int e = tid; e < 8192; e += 1024) {
        int row = e >> 6;
        int kc  = (e & 63) << 3;
        int gemm = row >> 6, r2 = row & 63, g = r2 >> 4, rl = r2 & 15;
        const float* src = Wg[gemm] + (size_t)(g * HID + jbase + rl) * HID + kc;
        short8 v = load8f(src);
        int kt = kc >> 5, q = (kc >> 3) & 3;
        int fragslot = ((gemm * 4 + g) * 16 + kt) * 64 + (q * 16 + rl);
        *(short8*)&lw[(size_t)fragslot * 8] = v;
    }

    // ---- per-lane persistent state ----
    const int jj = jbase + l16;
    float bias[4], c_r[4];
#pragma unroll
    for (int g = 0; g < 4; ++g)
        bias[g] = b_ih[l * G4H + g * HID + jj] + b_hh[l * G4H + g * HID + jj];
#pragma unroll
    for (int r = 0; r < 4; ++r)
        c_r[r] = c0[(size_t)l * BH + (size_t)(m16 + quad * 4 + r) * HID + jj];

    const short* lwb = lw + (size_t)lane * 8;
    // within-slice byte offset of this lane's A-row piece
    const int shi = quad >> 1;                // slice parity from quad
    const int abyte = (int)(((m16 + l16) * 16 + (quad & 1) * 8) * 2)
                    + shi * 8192;
    const srd_t hsrd = make_srd(hbuf);

    __syncthreads();

    for (int t = 0; t < SEQ; ++t) {
        // ---- dependency wait (tid0 polls, then barrier) ----
        if (tid == 0) {
            if (l > 0) {
                int need = 32 * (t + 1);
                while (__hip_atomic_load(&done[(l - 1) * 64], __ATOMIC_RELAXED,
                                         __HIP_MEMORY_SCOPE_AGENT) < need)
                    __builtin_amdgcn_s_sleep(1);
            }
            if (t > 0) {
                int need = 32 * t;
                while (__hip_atomic_load(&done[l * 64], __ATOMIC_RELAXED,
                                         __HIP_MEMORY_SCOPE_AGENT) < need)
                    __builtin_amdgcn_s_sleep(1);
            }
            if (l < NL - 1 && t >= 2) {
                int need = 32 * (t - 1);
                while (__hip_atomic_load(&done[(l + 1) * 64], __ATOMIC_RELAXED,
                                         __HIP_MEMORY_SCOPE_AGENT) < need)
                    __builtin_amdgcn_s_sleep(1);
            }
        }
        __syncthreads();

        const int p = t & 1, pm1 = p ^ 1;
        const int vpr = (int)(2 * hidx(pm1, l, 0, 0, 0)) + abyte;

        float4v acc[4];
#pragma unroll
        for (int g = 0; g < 4; ++g) acc[g] = (float4v){0.f, 0.f, 0.f, 0.f};

        if (l == 0) {
            int tok = x[t * BATCH + m16 + l16];
            const float* ar = emb + (size_t)tok * HID;
            // depth-4 rotate on hprev (emb is normal cached loads)
            short8 ah[4];
#pragma unroll
            for (int d = 0; d < 4; ++d)
                ah[d] = bload16(hsrd, vpr, d * 16384);
#pragma unroll
            for (int kt = 0; kt < 16; ++kt) {
                short8 a_in = load8f(ar + kt * 32 + quad * 8);
                short8 a_h = ah[kt & 3];
                if (kt + 4 < 16)
                    ah[kt & 3] = bload16(hsrd, vpr, (kt + 4) * 16384);
#pragma unroll
                for (int g = 0; g < 4; ++g) {
                    short8 b0 = *(const short8*)(lwb + (size_t)(g * 16 + kt) * 512);
                    short8 b1 = *(const short8*)(lwb + (size_t)((4 + g) * 16 + kt) * 512);
                    acc[g] = __builtin_amdgcn_mfma_f32_16x16x32_bf16(a_in, b0, acc[g], 0, 0, 0);
                    acc[g] = __builtin_amdgcn_mfma_f32_16x16x32_bf16(a_h,  b1, acc[g], 0, 0, 0);
                }
            }
        } else {
            const int vin = (int)(2 * hidx(p, l - 1, 0, 0, 0)) + abyte;
            short8 ai[4], ah[4];
#pragma unroll
            for (int d = 0; d < 4; ++d) {
                ai[d] = bload16(hsrd, vin, d * 16384);
                ah[d] = bload16(hsrd, vpr, d * 16384);
            }
#pragma unroll
            for (int kt = 0; kt < 16; ++kt) {
                short8 a_in = ai[kt & 3];
                short8 a_h  = ah[kt & 3];
                if (kt + 4 < 16) {
                    ai[kt & 3] = bload16(hsrd, vin, (kt + 4) * 16384);
                    ah[kt & 3] = bload16(hsrd, vpr, (kt + 4) * 16384);
                }
#pragma unroll
                for (int g = 0; g < 4; ++g) {
                    short8 b0 = *(const short8*)(lwb + (size_t)(g * 16 + kt) * 512);
                    short8 b1 = *(const short8*)(lwb + (size_t)((4 + g) * 16 + kt) * 512);
                    acc[g] = __builtin_amdgcn_mfma_f32_16x16x32_bf16(a_in, b0, acc[g], 0, 0, 0);
                    acc[g] = __builtin_amdgcn_mfma_f32_16x16x32_bf16(a_h,  b1, acc[g], 0, 0, 0);
                }
            }
        }

        // ---- epilogue: register c; per-wave LDS transpose of the 16x16
        //      output tile, then 32 lanes x 16B LLC-direct stores (8 full
        //      lines/wave vs 16 partial-line 2B RMWs) ----
        short* xp = (short*)&xch[wave];
#pragma unroll
        for (int r = 0; r < 4; ++r) {
            float iv = sigmoid_f(acc[0][r] + bias[0]);
            float fv = sigmoid_f(acc[1][r] + bias[1]);
            float gv = tanh_f(acc[2][r] + bias[2]);
            float ov = sigmoid_f(acc[3][r] + bias[3]);
            c_r[r] = fv * c_r[r] + iv * gv;
            xp[(quad * 4 + r) * 16 + l16] = bf16bits(ov * tanh_f(c_r[r]));
        }
        __builtin_amdgcn_wave_barrier();      // order LDS write -> read in-wave
        if (lane < 32) {
            short8 v = *(const short8*)&xp[lane * 8];
            int vout = (int)(2 * hidx(p, l, j, m16, 0)) + lane * 16;
            bstore16(v, hsrd, vout);
        }

        __syncthreads();   // all waves' stores drained (vmcnt) before flag
        if (tid == 0)
            __hip_atomic_fetch_add(&done[l * 64], 1, __ATOMIC_RELEASE,
                                   __HIP_MEMORY_SCOPE_AGENT);
    }
}

// ---------------------------------------------------------------------------
// output projection: out(256 x 32000) = h_final @ W_out^T + b_out
// 500 blocks x 512 thr; A = bf16 h (slice layout, cross-kernel visible),
// B = fp32 W_out streamed.
// ---------------------------------------------------------------------------
__global__ __launch_bounds__(512) void out_gemm_k(
    const __hip_bfloat16* __restrict__ hbuf,
    const float* __restrict__ W_out,
    const float* __restrict__ b_out,
    float* __restrict__ out)
{
    const int nb = blockIdx.x;
    const int tid = threadIdx.x;
    const int wave = tid >> 6, lane = tid & 63;
    const int quad = lane >> 4, l16 = lane & 15;
    const int nt = wave & 3, mh = wave >> 2;

    const __hip_bfloat16* hfin = hbuf + hidx(1, NL - 1, 0, 0, 0);
    const int shi = quad >> 1;
    const size_t coff = (size_t)(quad & 1) * 8;

    const int ncol = nb * 64 + nt * 16 + l16;
    const float* brow = W_out + (size_t)ncol * HID;

    float4v acc[8];
#pragma unroll
    for (int mt = 0; mt < 8; ++mt) acc[mt] = (float4v){0.f, 0.f, 0.f, 0.f};

#pragma unroll 2
    for (int kt = 0; kt < 16; ++kt) {
        short8 b = load8f(brow + kt * 32 + quad * 8);
        const __hip_bfloat16* abase =
            hfin + (size_t)(2 * kt + shi) * 4096 + coff;
#pragma unroll
        for (int mt = 0; mt < 8; ++mt) {
            short8 a = load8b(abase + (size_t)(mh * 128 + mt * 16 + l16) * 16);
            acc[mt] = __builtin_amdgcn_mfma_f32_16x16x32_bf16(a, b, acc[mt], 0, 0, 0);
        }
    }

    float bo = b_out[ncol];
#pragma unroll
    for (int mt = 0; mt < 8; ++mt) {
#pragma unroll
        for (int r = 0; r < 4; ++r) {
            int m = mh * 128 + mt * 16 + quad * 4 + r;
            out[(size_t)m * VOCAB + ncol] = acc[mt][r] + bo;
        }
    }
}

extern "C" void kernel_launch(void* const* d_in, const int* in_sizes, int n_in,
                              void* d_out, int out_size, void* d_ws, size_t ws_size,
                              hipStream_t stream) {
    const int* x        = (const int*)d_in[0];
    const float* h0     = (const float*)d_in[1];
    const float* c0     = (const float*)d_in[2];
    const float* emb    = (const float*)d_in[3];
    const float* W_ih   = (const float*)d_in[4];
    const float* W_hh   = (const float*)d_in[5];
    const float* b_ih   = (const float*)d_in[6];
    const float* b_hh   = (const float*)d_in[7];
    const float* W_out  = (const float*)d_in[8];
    const float* b_out  = (const float*)d_in[9];
    float* out          = (float*)d_out;

    // ws: h parity double-buffer (2,NL,B,H) bf16 slice layout | done counters
    __hip_bfloat16* hbuf = (__hip_bfloat16*)d_ws;
    int* done = (int*)((char*)d_ws + (size_t)2 * NL * BH * sizeof(__hip_bfloat16));

    init_state_k<<<(NL * BH) / 256, 256, 0, stream>>>(h0, hbuf, done);

    lstm_persist_k<<<NBLK, 1024, 0, stream>>>(x, emb, W_ih, W_hh, b_ih, b_hh,
                                              c0, hbuf, done);

    out_gemm_k<<<VOCAB / 64, 512, 0, stream>>>(hbuf, W_out, b_out, out);
}

// Round 3
// 3014.476 us; speedup vs baseline: 1.2087x; 1.0603x over previous
//
#include <hip/hip_runtime.h>
#include <hip/hip_bf16.h>

#define VOCAB 32000
#define HID 512
#define BATCH 256
#define SEQ 128
#define NL 5
#define BH (BATCH*HID)      // 131072
#define G4H (4*HID)         // 2048
#define NBLK 160            // 5 layers x 32 column-slices, 1 block/CU

typedef __attribute__((ext_vector_type(8))) short short8;
typedef __attribute__((ext_vector_type(4))) float float4v;
typedef __attribute__((ext_vector_type(4))) unsigned int uint4v;

__device__ __forceinline__ float sigmoid_f(float x) {
    return 1.f / (1.f + __expf(-x));
}
__device__ __forceinline__ float tanh_f(float x) {
    float ax = fabsf(x);
    float e = __expf(2.f * ax);
    float t = 1.f - 2.f / (e + 1.f);
    return copysignf(t, x);
}
__device__ __forceinline__ short bf16bits(float f) {
    union { __hip_bfloat16 b; short s; } u;
    u.b = __float2bfloat16(f);
    return u.s;
}
__device__ __forceinline__ short8 load8f(const float* p) {   // fp32 -> bf16 frag
    float4v lo = *(const float4v*)p;
    float4v hi = *(const float4v*)(p + 4);
    short8 r;
    r[0] = bf16bits(lo[0]); r[1] = bf16bits(lo[1]);
    r[2] = bf16bits(lo[2]); r[3] = bf16bits(lo[3]);
    r[4] = bf16bits(hi[0]); r[5] = bf16bits(hi[1]);
    r[6] = bf16bits(hi[2]); r[7] = bf16bits(hi[3]);
    return r;
}
__device__ __forceinline__ short8 load8b(const __hip_bfloat16* p) {
    return *(const short8*)p;
}

// ---------------------------------------------------------------------------
// LLC-direct (bypass L1+L2) wide load/store via raw buffer ops (sc0|sc1=17).
// Stores: write-through to the coherence point (needed for cross-XCD
// visibility; a plain writeback store strands dirty data in producer L2).
// Loads: only used by the fallback (small-ws) path, where the parity-2 h
// buffer reuses addresses and consumer L2s could be stale.
// ---------------------------------------------------------------------------
#if __has_builtin(__builtin_amdgcn_make_buffer_rsrc) && \
    __has_builtin(__builtin_amdgcn_raw_buffer_load_b128) && \
    __has_builtin(__builtin_amdgcn_raw_buffer_store_b128)
typedef __amdgpu_buffer_rsrc_t srd_t;
__device__ __forceinline__ srd_t make_srd(const void* p) {
    return __builtin_amdgcn_make_buffer_rsrc(const_cast<void*>(p), (short)0,
                                             0xFFFFFFFFu, 0x00020000);
}
__device__ __forceinline__ short8 bload16(srd_t srd, int voff, int soff) {
    union { uint4v u; short8 s; } c;
    c.u = __builtin_amdgcn_raw_buffer_load_b128(srd, voff, soff, 17);
    return c.s;
}
__device__ __forceinline__ void bstore16(short8 v, srd_t srd, int voff) {
    union { uint4v u; short8 s; } c; c.s = v;
    __builtin_amdgcn_raw_buffer_store_b128(c.u, srd, voff, 0, 17);
}
#else
typedef const char* srd_t;
__device__ __forceinline__ srd_t make_srd(const void* p) {
    return (const char*)p;
}
__device__ __forceinline__ short8 bload16(srd_t srd, int voff, int soff) {
    const char* base = srd + voff + soff;
    union { unsigned long long q[2]; short8 s; } u;
    u.q[0] = __hip_atomic_load((const unsigned long long*)base,
                               __ATOMIC_RELAXED, __HIP_MEMORY_SCOPE_AGENT);
    u.q[1] = __hip_atomic_load((const unsigned long long*)(base + 8),
                               __ATOMIC_RELAXED, __HIP_MEMORY_SCOPE_AGENT);
    return u.s;
}
__device__ __forceinline__ void bstore16(short8 v, srd_t srd, int voff) {
    char* base = const_cast<char*>(srd) + voff;
    union { unsigned long long q[2]; short8 s; } u; u.s = v;
    __hip_atomic_store((unsigned long long*)base, u.q[0],
                       __ATOMIC_RELAXED, __HIP_MEMORY_SCOPE_AGENT);
    __hip_atomic_store((unsigned long long*)(base + 8), u.q[1],
                       __ATOMIC_RELAXED, __HIP_MEMORY_SCOPE_AGENT);
}
#endif

// h layout: slot-contiguous [s][l][j(32)][m(256)][c(16)] bf16.
// BIGWS path: s = 0..SEQ (slot s = state after s steps; written once, read
// once -> no address reuse -> consumers may use plain cached loads, per-XCD
// L2 absorbs the 32x col-split read amplification).
// Fallback path: s = parity 0/1 (round-2 behavior, sc1 consumer loads).
__host__ __device__ constexpr size_t hidx(int s, int l, int j, int m, int c) {
    return ((((size_t)s * NL + l) * 32 + j) * 256 + m) * 16 + c;
}

// template<BIGWS> consumer fragment load
template<int BIGWS>
__device__ __forceinline__ short8 hload(const __hip_bfloat16* hbuf, srd_t srd,
                                        size_t off, int d) {
    if constexpr (BIGWS) {
        return *(const short8*)((const char*)hbuf + off + (size_t)d * 16384);
    } else {
        return bload16(srd, (int)off, d * 16384);
    }
}

// ---------------------------------------------------------------------------
// init: h0 fp32 -> bf16 h buffer slot `islot`; zero done counters
// ---------------------------------------------------------------------------
__global__ void init_state_k(const float* __restrict__ h0,
                             __hip_bfloat16* __restrict__ hbuf,
                             int* __restrict__ done, int islot) {
    int i = blockIdx.x * 256 + threadIdx.x;   // grid covers NL*BH exactly
    int l = i / BH, r = i % BH;
    int m = r >> 9, col = r & 511;
    hbuf[hidx(islot, l, col >> 4, m, col & 15)] = __float2bfloat16(h0[i]);
    if (blockIdx.x == 0 && threadIdx.x < NL) done[threadIdx.x * 64] = 0;
}

// ---------------------------------------------------------------------------
// persistent wavefront LSTM. block = (layer l, 16-col slice j); 16 waves,
// wave w owns rows [16w,16w+16). Weights bf16 in LDS (128 KB, frag order).
// c in registers. h: sc1 write-through stores (cross-XCD visibility);
// consumer loads are plain-cached (BIGWS, fresh addresses) or sc1 (fallback).
// Flags: monotonic per-layer counters.
// ---------------------------------------------------------------------------
template<int BIGWS>
__global__ __launch_bounds__(1024) void lstm_persist_k(
    const int* __restrict__ x,
    const float* __restrict__ emb,
    const float* __restrict__ W_ih,
    const float* __restrict__ W_hh,
    const float* __restrict__ b_ih,
    const float* __restrict__ b_hh,
    const float* __restrict__ c0,
    __hip_bfloat16* __restrict__ hbuf,
    int* __restrict__ done)
{
    __shared__ short lw[65536];               // 128 KB weight slice
    __shared__ short8 xch[16][32];            // 8 KB per-wave store transpose

    const int tid = threadIdx.x;
    const int xcd = blockIdx.x & 7;
    const int ixc = blockIdx.x >> 3;
    const int slot = xcd * 20 + ixc;          // XCD-contiguous slots
    const int l = slot >> 5;                  // layer 0..4
    const int j = slot & 31;                  // col slice 0..31
    const int jbase = j << 4;

    const int wave = tid >> 6, lane = tid & 63;
    const int quad = lane >> 4, l16 = lane & 15;
    const int m16 = wave << 4;

    const float* Wg[2] = { W_ih + (size_t)l * G4H * HID,
                           W_hh + (size_t)l * G4H * HID };

    // ---- stage weight slice into LDS in fragment order ----
    for (int e = tid; e < 8192; e += 1024) {
        int row = e >> 6;
        int kc  = (e & 63) << 3;
        int gemm = row >> 6, r2 = row & 63, g = r2 >> 4, rl = r2 & 15;
        const float* src = Wg[gemm] + (size_t)(g * HID + jbase + rl) * HID + kc;
        short8 v = load8f(src);
        int kt = kc >> 5, q = (kc >> 3) & 3;
        int fragslot = ((gemm * 4 + g) * 16 + kt) * 64 + (q * 16 + rl);
        *(short8*)&lw[(size_t)fragslot * 8] = v;
    }

    // ---- per-lane persistent state ----
    const int jj = jbase + l16;
    float bias[4], c_r[4];
#pragma unroll
    for (int g = 0; g < 4; ++g)
        bias[g] = b_ih[l * G4H + g * HID + jj] + b_hh[l * G4H + g * HID + jj];
#pragma unroll
    for (int r = 0; r < 4; ++r)
        c_r[r] = c0[(size_t)l * BH + (size_t)(m16 + quad * 4 + r) * HID + jj];

    const short* lwb = lw + (size_t)lane * 8;
    // within-slice byte offset of this lane's A-row piece
    const int shi = quad >> 1;                // slice parity from quad
    const size_t abyte = (size_t)(((m16 + l16) * 16 + (quad & 1) * 8) * 2)
                       + (size_t)shi * 8192;
    const srd_t hsrd = make_srd(hbuf);

    __syncthreads();

    for (int t = 0; t < SEQ; ++t) {
        // ---- dependency wait (tid0 polls, then barrier) ----
        if (tid == 0) {
            if (l > 0) {
                int need = 32 * (t + 1);
                while (__hip_atomic_load(&done[(l - 1) * 64], __ATOMIC_RELAXED,
                                         __HIP_MEMORY_SCOPE_AGENT) < need)
                    __builtin_amdgcn_s_sleep(1);
            }
            if (t > 0) {
                int need = 32 * t;
                while (__hip_atomic_load(&done[l * 64], __ATOMIC_RELAXED,
                                         __HIP_MEMORY_SCOPE_AGENT) < need)
                    __builtin_amdgcn_s_sleep(1);
            }
            if constexpr (!BIGWS) {
                // WAR throttle only needed when h addresses are reused
                if (l < NL - 1 && t >= 2) {
                    int need = 32 * (t - 1);
                    while (__hip_atomic_load(&done[(l + 1) * 64], __ATOMIC_RELAXED,
                                             __HIP_MEMORY_SCOPE_AGENT) < need)
                        __builtin_amdgcn_s_sleep(1);
                }
            }
        }
        __syncthreads();

        // slot indices: BIGWS reads slot t (own) / t+1 (layer below, its
        // step-t output), writes slot t+1. Fallback: parity as in round 2.
        const int p = t & 1, pm1 = p ^ 1;
        const int rslot_prev = BIGWS ? t : pm1;
        const int rslot_in   = BIGWS ? (t + 1) : p;
        const int wslot      = BIGWS ? (t + 1) : p;

        const size_t vpr = 2 * hidx(rslot_prev, l, 0, 0, 0) + abyte;

        float4v acc[4];
#pragma unroll
        for (int g = 0; g < 4; ++g) acc[g] = (float4v){0.f, 0.f, 0.f, 0.f};

        if (l == 0) {
            int tok = x[t * BATCH + m16 + l16];
            const float* ar = emb + (size_t)tok * HID;
            // depth-4 rotate on hprev (emb is normal cached loads)
            short8 ah[4];
#pragma unroll
            for (int d = 0; d < 4; ++d)
                ah[d] = hload<BIGWS>(hbuf, hsrd, vpr, d);
#pragma unroll
            for (int kt = 0; kt < 16; ++kt) {
                short8 a_in = load8f(ar + kt * 32 + quad * 8);
                short8 a_h = ah[kt & 3];
                if (kt + 4 < 16)
                    ah[kt & 3] = hload<BIGWS>(hbuf, hsrd, vpr, kt + 4);
#pragma unroll
                for (int g = 0; g < 4; ++g) {
                    short8 b0 = *(const short8*)(lwb + (size_t)(g * 16 + kt) * 512);
                    short8 b1 = *(const short8*)(lwb + (size_t)((4 + g) * 16 + kt) * 512);
                    acc[g] = __builtin_amdgcn_mfma_f32_16x16x32_bf16(a_in, b0, acc[g], 0, 0, 0);
                    acc[g] = __builtin_amdgcn_mfma_f32_16x16x32_bf16(a_h,  b1, acc[g], 0, 0, 0);
                }
            }
        } else {
            const size_t vin = 2 * hidx(rslot_in, l - 1, 0, 0, 0) + abyte;
            short8 ai[4], ah[4];
#pragma unroll
            for (int d = 0; d < 4; ++d) {
                ai[d] = hload<BIGWS>(hbuf, hsrd, vin, d);
                ah[d] = hload<BIGWS>(hbuf, hsrd, vpr, d);
            }
#pragma unroll
            for (int kt = 0; kt < 16; ++kt) {
                short8 a_in = ai[kt & 3];
                short8 a_h  = ah[kt & 3];
                if (kt + 4 < 16) {
                    ai[kt & 3] = hload<BIGWS>(hbuf, hsrd, vin, kt + 4);
                    ah[kt & 3] = hload<BIGWS>(hbuf, hsrd, vpr, kt + 4);
                }
#pragma unroll
                for (int g = 0; g < 4; ++g) {
                    short8 b0 = *(const short8*)(lwb + (size_t)(g * 16 + kt) * 512);
                    short8 b1 = *(const short8*)(lwb + (size_t)((4 + g) * 16 + kt) * 512);
                    acc[g] = __builtin_amdgcn_mfma_f32_16x16x32_bf16(a_in, b0, acc[g], 0, 0, 0);
                    acc[g] = __builtin_amdgcn_mfma_f32_16x16x32_bf16(a_h,  b1, acc[g], 0, 0, 0);
                }
            }
        }

        // ---- epilogue: register c; per-wave LDS transpose of the 16x16
        //      output tile, then 32 lanes x 16B write-through stores ----
        short* xp = (short*)&xch[wave];
#pragma unroll
        for (int r = 0; r < 4; ++r) {
            float iv = sigmoid_f(acc[0][r] + bias[0]);
            float fv = sigmoid_f(acc[1][r] + bias[1]);
            float gv = tanh_f(acc[2][r] + bias[2]);
            float ov = sigmoid_f(acc[3][r] + bias[3]);
            c_r[r] = fv * c_r[r] + iv * gv;
            xp[(quad * 4 + r) * 16 + l16] = bf16bits(ov * tanh_f(c_r[r]));
        }
        __builtin_amdgcn_wave_barrier();      // order LDS write -> read in-wave
        if (lane < 32) {
            short8 v = *(const short8*)&xp[lane * 8];
            int vout = (int)(2 * hidx(wslot, l, j, m16, 0)) + lane * 16;
            bstore16(v, hsrd, vout);
        }

        __syncthreads();   // all waves' stores drained (vmcnt) before flag
        if (tid == 0)
            __hip_atomic_fetch_add(&done[l * 64], 1, __ATOMIC_RELEASE,
                                   __HIP_MEMORY_SCOPE_AGENT);
    }
}

// ---------------------------------------------------------------------------
// output projection: out(256 x 32000) = h_final @ W_out^T + b_out
// 500 blocks x 512 thr; A = bf16 h (slice layout, cross-kernel visible),
// B = fp32 W_out streamed.
// ---------------------------------------------------------------------------
__global__ __launch_bounds__(512) void out_gemm_k(
    const __hip_bfloat16* __restrict__ hfin,
    const float* __restrict__ W_out,
    const float* __restrict__ b_out,
    float* __restrict__ out)
{
    const int nb = blockIdx.x;
    const int tid = threadIdx.x;
    const int wave = tid >> 6, lane = tid & 63;
    const int quad = lane >> 4, l16 = lane & 15;
    const int nt = wave & 3, mh = wave >> 2;

    const int shi = quad >> 1;
    const size_t coff = (size_t)(quad & 1) * 8;

    const int ncol = nb * 64 + nt * 16 + l16;
    const float* brow = W_out + (size_t)ncol * HID;

    float4v acc[8];
#pragma unroll
    for (int mt = 0; mt < 8; ++mt) acc[mt] = (float4v){0.f, 0.f, 0.f, 0.f};

#pragma unroll 2
    for (int kt = 0; kt < 16; ++kt) {
        short8 b = load8f(brow + kt * 32 + quad * 8);
        const __hip_bfloat16* abase =
            hfin + (size_t)(2 * kt + shi) * 4096 + coff;
#pragma unroll
        for (int mt = 0; mt < 8; ++mt) {
            short8 a = load8b(abase + (size_t)(mh * 128 + mt * 16 + l16) * 16);
            acc[mt] = __builtin_amdgcn_mfma_f32_16x16x32_bf16(a, b, acc[mt], 0, 0, 0);
        }
    }

    float bo = b_out[ncol];
#pragma unroll
    for (int mt = 0; mt < 8; ++mt) {
#pragma unroll
        for (int r = 0; r < 4; ++r) {
            int m = mh * 128 + mt * 16 + quad * 4 + r;
            out[(size_t)m * VOCAB + ncol] = acc[mt][r] + bo;
        }
    }
}

extern "C" void kernel_launch(void* const* d_in, const int* in_sizes, int n_in,
                              void* d_out, int out_size, void* d_ws, size_t ws_size,
                              hipStream_t stream) {
    const int* x        = (const int*)d_in[0];
    const float* h0     = (const float*)d_in[1];
    const float* c0     = (const float*)d_in[2];
    const float* emb    = (const float*)d_in[3];
    const float* W_ih   = (const float*)d_in[4];
    const float* W_hh   = (const float*)d_in[5];
    const float* b_ih   = (const float*)d_in[6];
    const float* b_hh   = (const float*)d_in[7];
    const float* W_out  = (const float*)d_in[8];
    const float* b_out  = (const float*)d_in[9];
    float* out          = (float*)d_out;

    __hip_bfloat16* hbuf = (__hip_bfloat16*)d_ws;

    // BIGWS: h rotates through SEQ+1 write-once slots (169 MB) -> consumers
    // use plain cached loads (per-XCD L2 absorbs the col-split read
    // amplification). Fallback: round-2 parity scheme (sc1 consumer loads).
    const size_t hbytes_big = (size_t)(SEQ + 1) * NL * BH * sizeof(__hip_bfloat16);
    const bool big = ws_size >= hbytes_big + 4096;

    if (big) {
        int* done = (int*)((char*)d_ws + hbytes_big);
        init_state_k<<<(NL * BH) / 256, 256, 0, stream>>>(h0, hbuf, done, 0);
        lstm_persist_k<1><<<NBLK, 1024, 0, stream>>>(x, emb, W_ih, W_hh, b_ih,
                                                     b_hh, c0, hbuf, done);
        out_gemm_k<<<VOCAB / 64, 512, 0, stream>>>(
            hbuf + hidx(SEQ, NL - 1, 0, 0, 0), W_out, b_out, out);
    } else {
        int* done = (int*)((char*)d_ws + (size_t)2 * NL * BH * sizeof(__hip_bfloat16));
        init_state_k<<<(NL * BH) / 256, 256, 0, stream>>>(h0, hbuf, done, 1);
        lstm_persist_k<0><<<NBLK, 1024, 0, stream>>>(x, emb, W_ih, W_hh, b_ih,
                                                     b_hh, c0, hbuf, done);
        out_gemm_k<<<VOCAB / 64, 512, 0, stream>>>(
            hbuf + hidx(1, NL - 1, 0, 0, 0), W_out, b_out, out);
    }
}